// Round 1
// baseline (1453.174 us; speedup 1.0000x reference)
//
#include <hip/hip_runtime.h>
#include <math.h>

// dims
#define Bv 2
#define Cv 64
#define Hv 512
#define Wv 512
#define Tv 16
#define GHv 32
#define GWv 32
#define Kv 1024
#define KMAXv 256
#define HIDv 128
#define HWv (Hv * Wv) // 262144

// output flat offsets (f32 elements)
#define OFF_HEAVY 0
#define OFF_DETAIL 33554432
#define OFF_ALPHA 67108864
#define OFF_PROB 67633152
#define OFF_GATES 67635200
#define OFF_EC 67637248
#define OFF_BL 67637249

// ws layout (bytes): selflag int[2048] @0 ; cost float[2] @8192 ; W2T float[8192] @12288
#define WS_SEL_OFF 0
#define WS_COST_OFF 8192
#define WS_W2T_OFF 12288

// ---------------- prep: transpose W2 [HID][C] -> W2T [C][HID] ----------------
__global__ __launch_bounds__(256) void prep_kernel(const float* __restrict__ W2,
                                                   float* __restrict__ W2T) {
    int tid = blockIdx.x * 256 + threadIdx.x; // 0..8191
    int c = tid >> 7;      // 0..63
    int d = tid & 127;     // 0..127
    W2T[tid] = W2[d * Cv + c];
}

// ---------------- selection + probabilities/gates + cost partials ----------------
__global__ __launch_bounds__(1024) void sel_kernel(const float* __restrict__ u,
                                                   float* __restrict__ out,
                                                   int* __restrict__ selflag,
                                                   float* __restrict__ costp) {
    int b = blockIdx.x;
    int t = threadIdx.x;
    __shared__ float us[Kv];
    __shared__ float red[16];

    float ui = u[b * Kv + t];
    us[t] = ui;
    __syncthreads();

    float p = 1.0f / (1.0f + __expf(-ui));
    float hard = (ui >= 0.0f) ? 1.0f : 0.0f;
    out[OFF_PROB + b * Kv + t] = p;
    out[OFF_GATES + b * Kv + t] = (hard + p) - p; // STE forward, same op order as ref

    // cost term: p*1.0 + (1-p)*0.1
    float cost = p + (1.0f - p) * 0.1f;
    #pragma unroll
    for (int o = 32; o > 0; o >>= 1) cost += __shfl_down(cost, o, 64);
    int wave = t >> 6, lane = t & 63;
    if (lane == 0) red[wave] = cost;
    __syncthreads();
    if (t == 0) {
        float s = 0.f;
        #pragma unroll
        for (int i = 0; i < 16; i++) s += red[i];
        costp[b] = s;
    }

    // rank among masked values (gate-fail -> -1e30, never beats ui>=0)
    int selected = 0;
    if (ui >= 0.0f) {
        int r = 0;
        for (int j = 0; j < Kv; j += 4) {
            float4 uj = *(const float4*)&us[j];
            r += (uj.x > ui) || (uj.x == ui && (j + 0) < t);
            r += (uj.y > ui) || (uj.y == ui && (j + 1) < t);
            r += (uj.z > ui) || (uj.z == ui && (j + 2) < t);
            r += (uj.w > ui) || (uj.w == ui && (j + 3) < t);
        }
        selected = (r < KMAXv) ? 1 : 0;
    }
    selflag[b * Kv + t] = selected;
}

// ---------------- main tile kernel: 2048 blocks x 256 threads ----------------
__global__ __launch_bounds__(256) void tile_kernel(const float* __restrict__ x,
                                                   const float* __restrict__ W1,
                                                   const float* __restrict__ b1,
                                                   const float* __restrict__ b2,
                                                   const float* __restrict__ Wa,
                                                   const float* __restrict__ ba,
                                                   float* __restrict__ out,
                                                   const int* __restrict__ selflag,
                                                   const float* __restrict__ costp,
                                                   const float* __restrict__ W2T) {
    int blk = blockIdx.x;
    int t = threadIdx.x;

    if (blk == 0 && t == 0) {
        float ec = costp[0] + costp[1];
        out[OFF_EC] = ec;
        out[OFF_BL] = (ec > 1024.0f) ? (ec - 1024.0f) : 0.0f; // MU=1, budget=512*B
    }

    int b = blk >> 10;
    int tile = blk & 1023;
    int gh = tile >> 5, gw = tile & 31;
    int h0 = gh * Tv, w0 = gw * Tv;

    int sel = selflag[blk];

    if (!sel) {
        // pure copy/zero path, float4 everywhere
        int cplane = t >> 6;         // 0..3
        int r = (t >> 2) & 15;       // row in tile
        int q = t & 3;               // float4 within row
        int base = ((b * Cv + cplane) * Hv + (h0 + r)) * Wv + w0 + q * 4;
        float4 z = make_float4(0.f, 0.f, 0.f, 0.f);
        #pragma unroll 4
        for (int c4 = 0; c4 < 16; c4++) {
            int idx = base + c4 * 4 * HWv;
            float4 v = *(const float4*)&x[idx];
            *(float4*)&out[OFF_HEAVY + idx] = v;
            *(float4*)&out[OFF_DETAIL + idx] = z;
        }
        if (t < 64) {
            int r2 = t >> 2, q2 = t & 3;
            int aidx = (b * Hv + h0 + r2) * Wv + w0 + q2 * 4;
            *(float4*)&out[OFF_ALPHA + aidx] = z;
        }
        return;
    }

    // ---- compute path: one thread per pixel ----
    int pw = t & 15, ph = t >> 4;
    int pbase = ((b * Cv + 0) * Hv + (h0 + ph)) * Wv + w0 + pw;

    float h_[HIDv];
    #pragma unroll
    for (int d = 0; d < HIDv; d += 4) {
        float4 bb = *(const float4*)&b1[d]; // uniform -> scalar load
        h_[d + 0] = bb.x; h_[d + 1] = bb.y; h_[d + 2] = bb.z; h_[d + 3] = bb.w;
    }
    float aacc = ba[0];

    // layer 1: h[d] += x_c * W1[c][d], W1 via uniform (scalar) loads
    float xc = x[pbase];
    for (int c = 0; c < Cv; c++) {
        float xn = (c < Cv - 1) ? x[pbase + (c + 1) * HWv] : 0.0f;
        aacc += xc * Wa[c];
        const float4* w1c = (const float4*)&W1[c * HIDv];
        #pragma unroll
        for (int d4 = 0; d4 < 32; d4++) {
            float4 w = w1c[d4];
            h_[4 * d4 + 0] += xc * w.x;
            h_[4 * d4 + 1] += xc * w.y;
            h_[4 * d4 + 2] += xc * w.z;
            h_[4 * d4 + 3] += xc * w.w;
        }
        xc = xn;
    }

    // gelu (tanh approx, matches jax.nn.gelu approximate=True)
    #pragma unroll
    for (int d = 0; d < HIDv; d++) {
        float zv = h_[d];
        float zz = 0.7978845608028654f * (zv + 0.044715f * zv * zv * zv);
        float e = __expf(2.0f * zz);
        float th = 1.0f - 2.0f / (e + 1.0f);
        h_[d] = 0.5f * zv * (1.0f + th);
    }

    float alpha = 1.0f / (1.0f + __expf(-aacc));
    out[OFF_ALPHA + (b * Hv + h0 + ph) * Wv + w0 + pw] = alpha;

    // layer 2 + epilogue: detail_c = b2[c] + sum_d h[d]*W2T[c][d]
    float xcur = x[pbase];
    for (int c = 0; c < Cv; c++) {
        float xn = (c < Cv - 1) ? x[pbase + (c + 1) * HWv] : 0.0f;
        const float4* w2c = (const float4*)&W2T[c * HIDv];
        float a0 = 0.f, a1 = 0.f, a2 = 0.f, a3 = 0.f;
        #pragma unroll
        for (int d4 = 0; d4 < 32; d4++) {
            float4 w = w2c[d4];
            a0 += h_[4 * d4 + 0] * w.x;
            a1 += h_[4 * d4 + 1] * w.y;
            a2 += h_[4 * d4 + 2] * w.z;
            a3 += h_[4 * d4 + 3] * w.w;
        }
        float det = b2[c] + ((a0 + a1) + (a2 + a3));
        int idx = pbase + c * HWv;
        out[OFF_DETAIL + idx] = det;
        out[OFF_HEAVY + idx] = xcur + alpha * det;
        xcur = xn;
    }
}

extern "C" void kernel_launch(void* const* d_in, const int* in_sizes, int n_in,
                              void* d_out, int out_size, void* d_ws, size_t ws_size,
                              hipStream_t stream) {
    const float* x  = (const float*)d_in[0];
    const float* u  = (const float*)d_in[1];
    const float* W1 = (const float*)d_in[2];
    const float* b1 = (const float*)d_in[3];
    const float* W2 = (const float*)d_in[4];
    const float* b2 = (const float*)d_in[5];
    const float* Wa = (const float*)d_in[6];
    const float* ba = (const float*)d_in[7];
    float* out = (float*)d_out;

    char* ws = (char*)d_ws;
    int*   selflag = (int*)(ws + WS_SEL_OFF);
    float* costp   = (float*)(ws + WS_COST_OFF);
    float* W2T     = (float*)(ws + WS_W2T_OFF);

    prep_kernel<<<32, 256, 0, stream>>>(W2, W2T);
    sel_kernel<<<Bv, 1024, 0, stream>>>(u, out, selflag, costp);
    tile_kernel<<<Bv * Kv, 256, 0, stream>>>(x, W1, b1, b2, Wa, ba, out, selflag, costp, W2T);
}

// Round 2
// 708.232 us; speedup vs baseline: 2.0518x; 2.0518x over previous
//
#include <hip/hip_runtime.h>
#include <math.h>

// dims
#define Bv 2
#define Cv 64
#define Hv 512
#define Wv 512
#define Tv 16
#define Kv 1024
#define KMAXv 256
#define HIDv 128
#define HWv (Hv * Wv) // 262144

// output flat offsets (f32 elements)
#define OFF_HEAVY 0
#define OFF_DETAIL 33554432
#define OFF_ALPHA 67108864
#define OFF_PROB 67633152
#define OFF_GATES 67635200
#define OFF_EC 67637248
#define OFF_BL 67637249

// ws layout (bytes): selflag int[2048] @0 ; cost float[2] @8192
#define WS_SEL_OFF 0
#define WS_COST_OFF 8192

// ---------------- selection + probabilities/gates + cost partials ----------------
__global__ __launch_bounds__(1024) void sel_kernel(const float* __restrict__ u,
                                                   float* __restrict__ out,
                                                   int* __restrict__ selflag,
                                                   float* __restrict__ costp) {
    int b = blockIdx.x;
    int t = threadIdx.x;
    __shared__ float us[Kv];
    __shared__ float red[16];

    float ui = u[b * Kv + t];
    us[t] = ui;
    __syncthreads();

    float p = 1.0f / (1.0f + __expf(-ui));
    float hard = (ui >= 0.0f) ? 1.0f : 0.0f;
    out[OFF_PROB + b * Kv + t] = p;
    out[OFF_GATES + b * Kv + t] = (hard + p) - p; // STE forward

    float cost = p + (1.0f - p) * 0.1f;
    #pragma unroll
    for (int o = 32; o > 0; o >>= 1) cost += __shfl_down(cost, o, 64);
    int wave = t >> 6, lane = t & 63;
    if (lane == 0) red[wave] = cost;
    __syncthreads();
    if (t == 0) {
        float s = 0.f;
        #pragma unroll
        for (int i = 0; i < 16; i++) s += red[i];
        costp[b] = s;
    }

    // rank among masked values
    int selected = 0;
    if (ui >= 0.0f) {
        int r = 0;
        for (int j = 0; j < Kv; j += 4) {
            float4 uj = *(const float4*)&us[j];
            r += (uj.x > ui) || (uj.x == ui && (j + 0) < t);
            r += (uj.y > ui) || (uj.y == ui && (j + 1) < t);
            r += (uj.z > ui) || (uj.z == ui && (j + 2) < t);
            r += (uj.w > ui) || (uj.w == ui && (j + 3) < t);
        }
        selected = (r < KMAXv) ? 1 : 0;
    }
    selflag[b * Kv + t] = selected;
}

// ---------------- copy kernel: unselected tiles only, low-VGPR, BW-bound ----------------
__global__ __launch_bounds__(256) void copy_kernel(const float* __restrict__ x,
                                                   float* __restrict__ out,
                                                   const int* __restrict__ selflag,
                                                   const float* __restrict__ costp) {
    int blk = blockIdx.x;
    int t = threadIdx.x;

    if (blk == 0 && t == 0) {
        float ec = costp[0] + costp[1];
        out[OFF_EC] = ec;
        out[OFF_BL] = (ec > 1024.0f) ? (ec - 1024.0f) : 0.0f;
    }

    if (selflag[blk]) return;

    int b = blk >> 10;
    int tile = blk & 1023;
    int gh = tile >> 5, gw = tile & 31;
    int h0 = gh * Tv, w0 = gw * Tv;

    int cplane = t >> 6;         // 0..3
    int r = (t >> 2) & 15;       // row in tile
    int q = t & 3;               // float4 within row
    int base = ((b * Cv + cplane) * Hv + (h0 + r)) * Wv + w0 + q * 4;
    float4 z = make_float4(0.f, 0.f, 0.f, 0.f);
    #pragma unroll 4
    for (int c4 = 0; c4 < 16; c4++) {
        int idx = base + c4 * 4 * HWv;
        float4 v = *(const float4*)&x[idx];
        *(float4*)&out[OFF_HEAVY + idx] = v;
        *(float4*)&out[OFF_DETAIL + idx] = z;
    }
    if (t < 64) {
        int r2 = t >> 2, q2 = t & 3;
        int aidx = (b * Hv + h0 + r2) * Wv + w0 + q2 * 4;
        *(float4*)&out[OFF_ALPHA + aidx] = z;
    }
}

// ---------------- mlp kernel: selected tiles, hid-chunked, LDS-staged x ----------------
__global__ __launch_bounds__(256) void mlp_kernel(const float* __restrict__ x,
                                                  const float* __restrict__ W1,
                                                  const float* __restrict__ b1,
                                                  const float* __restrict__ W2,
                                                  const float* __restrict__ b2,
                                                  const float* __restrict__ Wa,
                                                  const float* __restrict__ ba,
                                                  float* __restrict__ out,
                                                  const int* __restrict__ selflag) {
    int blk = blockIdx.x;
    if (!selflag[blk]) return;

    __shared__ float xs[Cv][257]; // stride 257: (c + p) % 32 bank -> 2-way, free
    int t = threadIdx.x;
    int b = blk >> 10;
    int tile = blk & 1023;
    int gh = tile >> 5, gw = tile & 31;
    int h0 = gh * Tv, w0 = gw * Tv;

    int pr = t >> 4, pc = t & 15;
    int pbase = ((b * Cv) * Hv + (h0 + pr)) * Wv + w0 + pc; // channel-0 addr of my pixel

    // stage x tile into LDS: xs[c][pixel]
    #pragma unroll 8
    for (int c = 0; c < Cv; c++) xs[c][t] = x[pbase + c * HWv];
    __syncthreads();

    // alpha = sigmoid(x . Wa + ba)
    float aacc = ba[0];
    #pragma unroll 8
    for (int c = 0; c < Cv; c++) aacc += xs[c][t] * Wa[c];
    float alpha = 1.0f / (1.0f + __expf(-aacc));
    out[OFF_ALPHA + (b * Hv + h0 + pr) * Wv + w0 + pc] = alpha;

    // detail accumulators, init to b2
    float D[Cv];
    #pragma unroll
    for (int c4 = 0; c4 < 16; c4++) {
        float4 bb = *(const float4*)&b2[c4 * 4];
        D[4 * c4 + 0] = bb.x; D[4 * c4 + 1] = bb.y;
        D[4 * c4 + 2] = bb.z; D[4 * c4 + 3] = bb.w;
    }

    // hid-chunked two-layer MLP
    for (int d0 = 0; d0 < HIDv; d0 += 32) {
        float Hc[32];
        #pragma unroll
        for (int j4 = 0; j4 < 8; j4++) {
            float4 bb = *(const float4*)&b1[d0 + 4 * j4];
            Hc[4 * j4 + 0] = bb.x; Hc[4 * j4 + 1] = bb.y;
            Hc[4 * j4 + 2] = bb.z; Hc[4 * j4 + 3] = bb.w;
        }
        // layer 1: Hc[j] += x_c * W1[c][d0+j]  (weights wave-uniform)
        #pragma unroll 2
        for (int c = 0; c < Cv; c++) {
            float xc = xs[c][t];
            const float4* w1p = (const float4*)(W1 + c * HIDv + d0);
            #pragma unroll
            for (int j4 = 0; j4 < 8; j4++) {
                float4 w = w1p[j4];
                Hc[4 * j4 + 0] += xc * w.x;
                Hc[4 * j4 + 1] += xc * w.y;
                Hc[4 * j4 + 2] += xc * w.z;
                Hc[4 * j4 + 3] += xc * w.w;
            }
        }
        // gelu (tanh approx, matches jax.nn.gelu)
        #pragma unroll
        for (int j = 0; j < 32; j++) {
            float zv = Hc[j];
            float zz = 0.7978845608028654f * (zv + 0.044715f * zv * zv * zv);
            float e = __expf(2.0f * zz);
            float th = 1.0f - 2.0f / (e + 1.0f);
            Hc[j] = 0.5f * zv * (1.0f + th);
        }
        // layer 2: D[c] += Hc[j] * W2[d0+j][c]  (weights wave-uniform, native layout)
        #pragma unroll 2
        for (int j = 0; j < 32; j++) {
            float hj = Hc[j];
            const float4* w2p = (const float4*)(W2 + (d0 + j) * Cv);
            #pragma unroll
            for (int c4 = 0; c4 < 16; c4++) {
                float4 w = w2p[c4];
                D[4 * c4 + 0] += hj * w.x;
                D[4 * c4 + 1] += hj * w.y;
                D[4 * c4 + 2] += hj * w.z;
                D[4 * c4 + 3] += hj * w.w;
            }
        }
    }

    // epilogue: detail_out, heavy
    #pragma unroll 4
    for (int c = 0; c < Cv; c++) {
        int idx = pbase + c * HWv;
        float det = D[c];
        out[OFF_DETAIL + idx] = det;
        out[OFF_HEAVY + idx] = xs[c][t] + alpha * det;
    }
}

extern "C" void kernel_launch(void* const* d_in, const int* in_sizes, int n_in,
                              void* d_out, int out_size, void* d_ws, size_t ws_size,
                              hipStream_t stream) {
    const float* x  = (const float*)d_in[0];
    const float* u  = (const float*)d_in[1];
    const float* W1 = (const float*)d_in[2];
    const float* b1 = (const float*)d_in[3];
    const float* W2 = (const float*)d_in[4];
    const float* b2 = (const float*)d_in[5];
    const float* Wa = (const float*)d_in[6];
    const float* ba = (const float*)d_in[7];
    float* out = (float*)d_out;

    char* ws = (char*)d_ws;
    int*   selflag = (int*)(ws + WS_SEL_OFF);
    float* costp   = (float*)(ws + WS_COST_OFF);

    sel_kernel<<<Bv, 1024, 0, stream>>>(u, out, selflag, costp);
    copy_kernel<<<Bv * Kv, 256, 0, stream>>>(x, out, selflag, costp);
    mlp_kernel<<<Bv * Kv, 256, 0, stream>>>(x, W1, b1, W2, b2, Wa, ba, out, selflag);
}